// Round 1
// baseline (204.796 us; speedup 1.0000x reference)
//
#include <hip/hip_runtime.h>
#include <hip/hip_bf16.h>

#define BIG 1e30f

typedef __attribute__((ext_vector_type(8))) unsigned short ushort8;

// ---------------- Phase 0: row sum-of-squares (x2 / y2) ----------------
// 16 lanes per row of 64 floats (one float4 each), shfl-reduce within the 16.
__global__ __launch_bounds__(256) void sumsq_kernel(const float* __restrict__ in,
                                                    float* __restrict__ out,
                                                    int nrows) {
    int gid = blockIdx.x * 256 + threadIdx.x;
    int row = gid >> 4;
    int l   = gid & 15;
    if (row >= nrows) return;
    const float4* p = reinterpret_cast<const float4*>(in + (size_t)row * 64);
    float4 v = p[l];
    float s = v.x*v.x + v.y*v.y + v.z*v.z + v.w*v.w;
    s += __shfl_xor(s, 8);
    s += __shfl_xor(s, 4);
    s += __shfl_xor(s, 2);
    s += __shfl_xor(s, 1);
    if (l == 0) out[row] = s;
}

// ---------------- Phase 1: D = x2 + y2 - 2*x.y^T, bf16, diag-major ----------------
// One block = one batch's 64x64 tile. 256 threads, 4x4 micro-tile, K=64 in one shot.
// Epilogue stages D in LDS then writes anti-diagonal-major: Dd[b][k=i+j][i].
__global__ __launch_bounds__(256) void gemm_diag_kernel(
    const float* __restrict__ x, const float* __restrict__ y,
    const float* __restrict__ x2g, const float* __restrict__ y2g,
    __hip_bfloat16* __restrict__ Dd)
{
    __shared__ float Xs[64][68];   // Xs[k][i]  (transposed; pad 68 keeps float4 align, no conflicts)
    __shared__ float Ys[64][68];   // Ys[k][j]
    const int b  = blockIdx.y;
    const int i0 = (blockIdx.x >> 3) * 64;
    const int j0 = (blockIdx.x & 7) * 64;
    const int t  = threadIdx.x;

    // stage X,Y tiles (coalesced float4 global reads, transposed LDS writes)
    {
        const int row = t >> 2, q = t & 3;
        const float4* xb = reinterpret_cast<const float4*>(x + (size_t)(b*512 + i0 + row) * 64);
        const float4* yb = reinterpret_cast<const float4*>(y + (size_t)(b*512 + j0 + row) * 64);
        #pragma unroll
        for (int ii = 0; ii < 4; ++ii) {
            int f = q + ii*4;
            float4 xv = xb[f];
            float4 yv = yb[f];
            int k = f*4;
            Xs[k+0][row] = xv.x; Xs[k+1][row] = xv.y; Xs[k+2][row] = xv.z; Xs[k+3][row] = xv.w;
            Ys[k+0][row] = yv.x; Ys[k+1][row] = yv.y; Ys[k+2][row] = yv.z; Ys[k+3][row] = yv.w;
        }
    }
    __syncthreads();

    const int r0 = (t >> 4) * 4;   // micro-tile row base (i)
    const int c0 = (t & 15) * 4;   // micro-tile col base (j)
    float acc[4][4] = {};
    #pragma unroll 4
    for (int k = 0; k < 64; ++k) {
        float4 xv = *reinterpret_cast<const float4*>(&Xs[k][r0]);
        float4 yv = *reinterpret_cast<const float4*>(&Ys[k][c0]);
        float xa[4] = {xv.x, xv.y, xv.z, xv.w};
        float ya[4] = {yv.x, yv.y, yv.z, yv.w};
        #pragma unroll
        for (int r = 0; r < 4; ++r)
            #pragma unroll
            for (int c = 0; c < 4; ++c)
                acc[r][c] += xa[r] * ya[c];
    }
    __syncthreads();   // done reading Xs/Ys; reuse Xs as the D staging buffer

    float xs2[4], ys2[4];
    #pragma unroll
    for (int r = 0; r < 4; ++r) xs2[r] = x2g[b*512 + i0 + r0 + r];
    #pragma unroll
    for (int c = 0; c < 4; ++c) ys2[c] = y2g[b*512 + j0 + c0 + c];
    #pragma unroll
    for (int r = 0; r < 4; ++r)
        #pragma unroll
        for (int c = 0; c < 4; ++c)
            Xs[r0+r][c0+c] = xs2[r] + ys2[c] - 2.0f * acc[r][c];
    __syncthreads();

    // write tile diagonals: local diag kk = (i-i0)+(j-j0) in [0,126]
    const int w = t >> 6, lane = t & 63;
    for (int it = 0; it < 32; ++it) {
        int kk = w + it*4;
        if (kk > 126) break;
        int jl = kk - lane;
        if (jl >= 0 && jl < 64) {
            float v = Xs[lane][jl];                    // addr = 67*lane + kk -> conflict-free
            size_t idx = ((size_t)(b*1023 + i0 + j0 + kk)) * 512 + (size_t)(i0 + lane);
            Dd[idx] = __float2bfloat16(v);
        }
    }
}

// ---------------- Phase 2: DTW wavefront, one wave per batch ----------------
// Lane t owns rows 8t..8t+7. r1 = diag k-1, r2 = diag k-2 (register-resident).
// Cross-lane dependency: 2 shfl_up per diagonal. D reads coalesced (diag-major),
// double-buffered in 16-diag chunks to hide HBM latency (only 128 waves total).
__global__ __launch_bounds__(64) void dtw_kernel(const __hip_bfloat16* __restrict__ Ddb,
                                                 float* __restrict__ out)
{
    const int b = blockIdx.x;
    const int t = threadIdx.x;
    const unsigned short* base =
        reinterpret_cast<const unsigned short*>(Ddb) + (size_t)b * 1023 * 512 + t * 8;

    float r1[8], r2[8];
    #pragma unroll
    for (int c = 0; c < 8; ++c) { r1[c] = BIG; r2[c] = BIG; }

    ushort8 bufA[16], bufB[16];

    auto load_chunk = [&](ushort8 (&buf)[16], int ch) {
        #pragma unroll
        for (int d = 0; d < 16; ++d) {
            int k = ch*16 + d; if (k > 1022) k = 1022;   // clamped dummy load
            buf[d] = *reinterpret_cast<const ushort8*>(base + (size_t)k * 512);
        }
    };
    auto compute_chunk = [&](ushort8 (&buf)[16], int k0) {
        #pragma unroll
        for (int d = 0; d < 16; ++d) {
            int k = k0 + d;
            if (k <= 1022) {
                ushort8 dv = buf[d];
                float up_in = __shfl_up(r1[7], 1);   // R[r-1][j]   from lane t-1
                float dg_in = __shfl_up(r2[7], 1);   // R[r-1][j-1] from lane t-1
                if (t == 0) { up_in = BIG; dg_in = (k == 0) ? 0.0f : BIG; }
                float nv[8];
                #pragma unroll
                for (int c = 0; c < 8; ++c) {
                    int r = t*8 + c;
                    int j = k - r;
                    float dval = __uint_as_float(((unsigned)dv[c]) << 16);
                    float pu = (c == 0) ? up_in : r1[c-1];   // up
                    float pd = (c == 0) ? dg_in : r2[c-1];   // diagonal
                    float pl = r1[c];                         // left
                    float v  = dval + fminf(fminf(pd, pu), pl);
                    nv[c] = (j >= 0 && j < 512) ? v : BIG;
                }
                #pragma unroll
                for (int c = 0; c < 8; ++c) { r2[c] = r1[c]; r1[c] = nv[c]; }
            }
        }
    };

    load_chunk(bufA, 0);
    for (int ch = 0; ch < 64; ch += 2) {
        load_chunk(bufB, ch + 1);
        compute_chunk(bufA, ch * 16);
        if (ch + 2 < 64) load_chunk(bufA, ch + 2);
        compute_chunk(bufB, (ch + 1) * 16);
    }

    if (t == 63) out[b] = r1[7];   // R[511][511]
}

// ---------------- launch ----------------
// ws layout: [x2: 65536 f32][y2: 65536 f32][Dd: 128*1023*512 bf16 = 134,086,656 B]
// total ws needed: 512KB + ~128MB = 134,610,944 bytes.
extern "C" void kernel_launch(void* const* d_in, const int* in_sizes, int n_in,
                              void* d_out, int out_size, void* d_ws, size_t ws_size,
                              hipStream_t stream) {
    const float* x = (const float*)d_in[0];
    const float* y = (const float*)d_in[1];
    float* out = (float*)d_out;
    char*  ws  = (char*)d_ws;

    float* x2 = (float*)ws;
    float* y2 = x2 + 128*512;
    __hip_bfloat16* Dd = (__hip_bfloat16*)(ws + 512*1024);

    // 128*512 rows, 16 lanes/row -> 1,048,576 threads -> 4096 blocks
    sumsq_kernel<<<4096, 256, 0, stream>>>(x, x2, 128*512);
    sumsq_kernel<<<4096, 256, 0, stream>>>(y, y2, 128*512);

    gemm_diag_kernel<<<dim3(64, 128), 256, 0, stream>>>(x, y, x2, y2, Dd);

    dtw_kernel<<<128, 64, 0, stream>>>(Dd, out);
}